// Round 1
// baseline (2085.980 us; speedup 1.0000x reference)
//
#include <hip/hip_runtime.h>

// Problem constants (GCNPre): N=100000 nodes, E=3200000 edges,
// F=512 in-feat, H=256 hidden, C=40 classes.
#define NN 100000
#define NE 3200000
#define NF 512
#define NH 256
#define NC 40

// ---------------- degree / CSR build ----------------

__global__ void hist_kernel(const int* __restrict__ ei, int* __restrict__ deg_cnt,
                            int* __restrict__ row_cnt, int E) {
    int e = blockIdx.x * blockDim.x + threadIdx.x;
    if (e >= E) return;
    int r = ei[e];        // row = edge_index[0][e]
    int c = ei[E + e];    // col = edge_index[1][e]
    atomicAdd(&deg_cnt[c], 1);
    atomicAdd(&row_cnt[r], 1);
}

__global__ void dis_kernel(const int* __restrict__ deg_cnt, float* __restrict__ dis, int n) {
    int i = blockIdx.x * blockDim.x + threadIdx.x;
    if (i >= n) return;
    dis[i] = rsqrtf((float)deg_cnt[i] + 1.0f);
}

// single-block exclusive scan of row_cnt -> row_ptr (n up to ~100k)
__global__ void scan_kernel(const int* __restrict__ cnt, int* __restrict__ ptr, int n, int total) {
    __shared__ int s[1024];
    int t = threadIdx.x;
    int chunk = (n + 1023) / 1024;
    int lo = t * chunk, hi = min(lo + chunk, n);
    int sum = 0;
    for (int i = lo; i < hi; i++) sum += cnt[i];
    s[t] = sum;
    __syncthreads();
    // Hillis-Steele inclusive scan
    for (int off = 1; off < 1024; off <<= 1) {
        int v = (t >= off) ? s[t - off] : 0;
        __syncthreads();
        s[t] += v;
        __syncthreads();
    }
    int run = (t == 0) ? 0 : s[t - 1];
    for (int i = lo; i < hi; i++) { ptr[i] = run; run += cnt[i]; }
    if (t == 0) ptr[n] = total;
}

__global__ void fill_kernel(const int* __restrict__ ei, const int* __restrict__ row_ptr,
                            int* __restrict__ cur, const float* __restrict__ dis,
                            int* __restrict__ csr_col, float* __restrict__ csr_w, int E) {
    int e = blockIdx.x * blockDim.x + threadIdx.x;
    if (e >= E) return;
    int r = ei[e];
    int c = ei[E + e];
    int p = atomicAdd(&cur[r], 1);
    int idx = row_ptr[r] + p;
    csr_col[idx] = c;
    csr_w[idx] = dis[r] * dis[c];
}

// ---------------- fp32 tiled GEMM ----------------
// C[M,N] = op(A[M,K] @ B[K,N] (+bias) (relu))
template <int BM, int BN, int BK, int TM, int TN, bool BIAS, bool RELU>
__global__ __launch_bounds__(256) void gemm_kernel(const float* __restrict__ A,
                                                   const float* __restrict__ B,
                                                   const float* __restrict__ bias,
                                                   float* __restrict__ C,
                                                   int M, int N, int K) {
    constexpr int TX = BN / TN;
    constexpr int TY = BM / TM;
    static_assert(TX * TY == 256, "256 threads");
    constexpr int A_LOADS = (BM * BK) / (256 * 4);
    constexpr int B_LOADS = (BK * BN) / (256 * 4);
    static_assert(A_LOADS >= 1 && B_LOADS >= 1, "load mapping");

    __shared__ float As[BK][BM];   // transposed A tile
    __shared__ float Bs[BK][BN];

    int tid = threadIdx.x;
    int tx = tid % TX, ty = tid / TX;
    int bm = blockIdx.x * BM, bn = blockIdx.y * BN;

    float acc[TM][TN] = {};

    for (int k0 = 0; k0 < K; k0 += BK) {
        // A tile: BM x BK, each thread A_LOADS float4s along K
        #pragma unroll
        for (int l = 0; l < A_LOADS; l++) {
            int t = tid + l * 256;
            int ar = t / (BK / 4);
            int ac = (t % (BK / 4)) * 4;
            int gr = bm + ar, gc = k0 + ac;
            float4 v = make_float4(0.f, 0.f, 0.f, 0.f);
            if (gr < M) v = *reinterpret_cast<const float4*>(&A[(long)gr * K + gc]);
            As[ac + 0][ar] = v.x;
            As[ac + 1][ar] = v.y;
            As[ac + 2][ar] = v.z;
            As[ac + 3][ar] = v.w;
        }
        // B tile: BK x BN
        #pragma unroll
        for (int l = 0; l < B_LOADS; l++) {
            int t = tid + l * 256;
            int br = t / (BN / 4);
            int bc = (t % (BN / 4)) * 4;
            int gr = k0 + br, gc = bn + bc;
            float4 v = make_float4(0.f, 0.f, 0.f, 0.f);
            if (gc + 3 < N) {
                v = *reinterpret_cast<const float4*>(&B[(long)gr * N + gc]);
            } else {
                float tmp[4] = {0.f, 0.f, 0.f, 0.f};
                for (int j = 0; j < 4; j++)
                    if (gc + j < N) tmp[j] = B[(long)gr * N + gc + j];
                v = make_float4(tmp[0], tmp[1], tmp[2], tmp[3]);
            }
            *reinterpret_cast<float4*>(&Bs[br][bc]) = v;
        }
        __syncthreads();

        #pragma unroll
        for (int kk = 0; kk < BK; kk++) {
            float a[TM], b[TN];
            #pragma unroll
            for (int i = 0; i < TM; i++) a[i] = As[kk][ty * TM + i];
            #pragma unroll
            for (int j = 0; j < TN; j++) b[j] = Bs[kk][tx * TN + j];
            #pragma unroll
            for (int i = 0; i < TM; i++)
                #pragma unroll
                for (int j = 0; j < TN; j++)
                    acc[i][j] = fmaf(a[i], b[j], acc[i][j]);
        }
        __syncthreads();
    }

    // epilogue
    #pragma unroll
    for (int i = 0; i < TM; i++) {
        int gr = bm + ty * TM + i;
        if (gr >= M) continue;
        #pragma unroll
        for (int j = 0; j < TN; j++) {
            int gc = bn + tx * TN + j;
            if (gc >= N) continue;
            float v = acc[i][j];
            if (BIAS) v += bias[gc];
            if (RELU) v = fmaxf(v, 0.f);
            C[(long)gr * N + gc] = v;
        }
    }
}

// ---------------- aggregation (gather SpMM) ----------------
// out[node,f] = relu( sum_e w[e]*t[col[e],f] + t[node,f]*dis[node]^2 + bias[f] )
template <bool RELU>
__global__ void agg256_kernel(const float* __restrict__ t, const int* __restrict__ row_ptr,
                              const int* __restrict__ csr_col, const float* __restrict__ csr_w,
                              const float* __restrict__ dis, const float* __restrict__ bias,
                              float* __restrict__ out, int n) {
    int node = blockIdx.x;
    int f = threadIdx.x;   // 256 threads = 256 features
    float d = dis[node];
    float acc = t[(long)node * NH + f] * (d * d);
    int lo = row_ptr[node], hi = row_ptr[node + 1];
    for (int e = lo; e < hi; e++) {
        int c = csr_col[e];
        float w = csr_w[e];
        acc = fmaf(t[(long)c * NH + f], w, acc);
    }
    acc += bias[f];
    if (RELU) acc = fmaxf(acc, 0.f);
    out[(long)node * NH + f] = acc;
}

__global__ void agg40_kernel(const float* __restrict__ t, const int* __restrict__ row_ptr,
                             const int* __restrict__ csr_col, const float* __restrict__ csr_w,
                             const float* __restrict__ dis, const float* __restrict__ bias,
                             float* __restrict__ out, int n) {
    int node = blockIdx.x;
    int f = threadIdx.x;   // 64 threads, 40 active
    if (f >= NC) return;
    float d = dis[node];
    float acc = t[(long)node * NC + f] * (d * d);
    int lo = row_ptr[node], hi = row_ptr[node + 1];
    for (int e = lo; e < hi; e++) {
        int c = csr_col[e];
        float w = csr_w[e];
        acc = fmaf(t[(long)c * NC + f], w, acc);
    }
    out[(long)node * NC + f] = acc + bias[f];
}

// ---------------- launch ----------------

extern "C" void kernel_launch(void* const* d_in, const int* in_sizes, int n_in,
                              void* d_out, int out_size, void* d_ws, size_t ws_size,
                              hipStream_t stream) {
    const float* x     = (const float*)d_in[0];
    const int*   ei    = (const int*)d_in[1];
    const float* W_mlp = (const float*)d_in[2];
    const float* b_mlp = (const float*)d_in[3];
    const float* W1    = (const float*)d_in[4];
    const float* b1    = (const float*)d_in[5];
    const float* W2    = (const float*)d_in[6];
    const float* b2    = (const float*)d_in[7];
    float* out = (float*)d_out;

    const int n = NN, E = NE;

    // workspace layout (floats), 128-float aligned chunks
    float* ws = (float*)d_ws;
    size_t off = 0;
    float* dis     = ws + off; off += 100096;          // n
    int*   deg_cnt = (int*)(ws + off); off += 100096;  // n
    int*   row_cnt = (int*)(ws + off); off += 100096;  // n
    int*   row_ptr = (int*)(ws + off); off += 100096;  // n+1
    int*   cur     = (int*)(ws + off); off += 100096;  // n
    int*   csr_col = (int*)(ws + off); off += NE;
    float* csr_w   = ws + off; off += NE;
    float* h0      = ws + off; off += (size_t)NN * NH; // also holds h1 later
    float* t1      = ws + off; off += (size_t)NN * NH;
    float* t2      = ws + off; off += (size_t)NN * NC;
    (void)ws_size;

    hipMemsetAsync(deg_cnt, 0, n * sizeof(int), stream);
    hipMemsetAsync(row_cnt, 0, n * sizeof(int), stream);
    hipMemsetAsync(cur, 0, n * sizeof(int), stream);

    int eb = (E + 255) / 256;
    hist_kernel<<<eb, 256, 0, stream>>>(ei, deg_cnt, row_cnt, E);
    dis_kernel<<<(n + 255) / 256, 256, 0, stream>>>(deg_cnt, dis, n);
    scan_kernel<<<1, 1024, 0, stream>>>(row_cnt, row_ptr, n, E);
    fill_kernel<<<eb, 256, 0, stream>>>(ei, row_ptr, cur, dis, csr_col, csr_w, E);

    // h0 = relu(x @ W_mlp + b_mlp)   [100000,512]x[512,256]
    {
        dim3 grid((NN + 127) / 128, (NH + 127) / 128);
        gemm_kernel<128, 128, 16, 8, 8, true, true>
            <<<grid, 256, 0, stream>>>(x, W_mlp, b_mlp, h0, NN, NH, NF);
    }
    // t1 = h0 @ W1                    [100000,256]x[256,256]
    {
        dim3 grid((NN + 127) / 128, (NH + 127) / 128);
        gemm_kernel<128, 128, 16, 8, 8, false, false>
            <<<grid, 256, 0, stream>>>(h0, W1, nullptr, t1, NN, NH, NH);
    }
    // h1 = relu(agg(t1) + b1) -> overwrite h0
    agg256_kernel<true><<<n, 256, 0, stream>>>(t1, row_ptr, csr_col, csr_w, dis, b1, h0, n);
    // t2 = h1 @ W2                    [100000,256]x[256,40]
    {
        dim3 grid((NN + 63) / 64, (NC + 63) / 64);
        gemm_kernel<64, 64, 16, 4, 4, false, false>
            <<<grid, 256, 0, stream>>>(h0, W2, nullptr, t2, NN, NC, NH);
    }
    // out = agg(t2) + b2
    agg40_kernel<<<n, 64, 0, stream>>>(t2, row_ptr, csr_col, csr_w, dis, b2, out, n);
}

// Round 2
// 1138.322 us; speedup vs baseline: 1.8325x; 1.8325x over previous
//
#include <hip/hip_runtime.h>

// GCNPre: N=100000 nodes, E=3200000 edges, F=512, H=256, C=40.
#define NN 100000
#define NE 3200000
#define NF 512
#define NH 256
#define NC 40

typedef __attribute__((ext_vector_type(8))) short bf16x8;
typedef __attribute__((ext_vector_type(4))) float f32x4;
typedef __attribute__((ext_vector_type(4))) unsigned short u16x4;

__device__ inline unsigned short f2bf(float f) {
    union { float f; unsigned u; } v; v.f = f;
    unsigned r = v.u + 0x7fffu + ((v.u >> 16) & 1u);
    return (unsigned short)(r >> 16);
}
__device__ inline float bf2f(unsigned short s) {
    union { unsigned u; float f; } v; v.u = ((unsigned)s) << 16;
    return v.f;
}

// ---------------- degree / CSR build ----------------

__global__ void hist_kernel(const int* __restrict__ ei, int* __restrict__ deg_cnt,
                            int* __restrict__ row_cnt, int E) {
    int e = blockIdx.x * blockDim.x + threadIdx.x;
    if (e >= E) return;
    int r = ei[e];
    int c = ei[E + e];
    atomicAdd(&deg_cnt[c], 1);
    atomicAdd(&row_cnt[r], 1);
}

__global__ void dis_kernel(const int* __restrict__ deg_cnt, float* __restrict__ dis, int n) {
    int i = blockIdx.x * blockDim.x + threadIdx.x;
    if (i >= n) return;
    dis[i] = rsqrtf((float)deg_cnt[i] + 1.0f);
}

__global__ void scan_kernel(const int* __restrict__ cnt, int* __restrict__ ptr, int n, int total) {
    __shared__ int s[1024];
    int t = threadIdx.x;
    int chunk = (n + 1023) / 1024;
    int lo = t * chunk, hi = min(lo + chunk, n);
    int sum = 0;
    for (int i = lo; i < hi; i++) sum += cnt[i];
    s[t] = sum;
    __syncthreads();
    for (int off = 1; off < 1024; off <<= 1) {
        int v = (t >= off) ? s[t - off] : 0;
        __syncthreads();
        s[t] += v;
        __syncthreads();
    }
    int run = (t == 0) ? 0 : s[t - 1];
    for (int i = lo; i < hi; i++) { ptr[i] = run; run += cnt[i]; }
    if (t == 0) ptr[n] = total;
}

__global__ void fill_kernel(const int* __restrict__ ei, const int* __restrict__ row_ptr,
                            int* __restrict__ cur, const float* __restrict__ dis,
                            int* __restrict__ csr_col, float* __restrict__ csr_w, int E) {
    int e = blockIdx.x * blockDim.x + threadIdx.x;
    if (e >= E) return;
    int r = ei[e];
    int c = ei[E + e];
    int p = atomicAdd(&cur[r], 1);
    int idx = row_ptr[r] + p;
    csr_col[idx] = c;
    csr_w[idx] = dis[r] * dis[c];
}

// ---------------- weight transpose + bf16 cast ----------------
// src [K][N] fp32 -> dst [NP][K] bf16 (rows n>=N zero-padded)
__global__ void wtrans_kernel(const float* __restrict__ src, unsigned short* __restrict__ dst,
                              int K, int N, int NP) {
    int t = blockIdx.x * blockDim.x + threadIdx.x;
    if (t >= K * NP) return;
    int k = t % K, n = t / K;
    dst[t] = (n < N) ? f2bf(src[(long)k * N + n]) : (unsigned short)0;
}

// ---------------- bf16 MFMA GEMM ----------------
// C[M,BN] = op(A[M,K] @ W[K,BN]) where W is given transposed: WT[BN][K] bf16.
// A is fp32 (A_F32) or bf16. Output bf16, ldc = BN. Single N-block (grid.y==1).
template <int BN, bool A_F32, bool BIAS, bool RELU>
__global__ __launch_bounds__(BN == 256 ? 512 : 256)
void gemm_mfma(const void* __restrict__ Ap, const unsigned short* __restrict__ WT,
               const float* __restrict__ bias, unsigned short* __restrict__ C,
               int M, int K) {
    constexpr int BM = 128, BK = 32;
    constexpr int T = (BN == 256) ? 512 : 256;
    constexpr int WN = (BN == 256) ? 2 : 1;     // wave columns
    constexpr int NREP = BN / (WN * 16);        // 8 or 4
    constexpr int MREP = 2;                     // 4 wave-rows * 2 * 16 = 128
    constexpr int ACH = (BM * BK) / 8;          // 8-elem chunks in A tile
    constexpr int BCH = (BN * BK) / 8;

    __shared__ short As[BM * BK];
    __shared__ short Bs[BN * BK];

    const int tid = threadIdx.x;
    const int lane = tid & 63;
    const int wid = tid >> 6;
    const int wr = wid / WN;       // 0..3
    const int wc = wid % WN;       // 0..WN-1
    const long bm = (long)blockIdx.x * BM;

    f32x4 acc[MREP][NREP];
    #pragma unroll
    for (int i = 0; i < MREP; i++)
        #pragma unroll
        for (int j = 0; j < NREP; j++)
            acc[i][j] = (f32x4){0.f, 0.f, 0.f, 0.f};

    const float* Af = (const float*)Ap;
    const unsigned short* Ab = (const unsigned short*)Ap;

    for (int k0 = 0; k0 < K; k0 += BK) {
        // stage A tile (BM x BK), 16B chunks, XOR-swizzled
        #pragma unroll
        for (int i = 0; i < ACH / T; i++) {
            int ch = tid + i * T;
            int row = ch >> 2, c = ch & 3;
            int sw = c ^ (row & 3) ^ ((row >> 2) & 3);
            long gr = bm + row;
            bf16x8 w;
            if (gr < M) {
                if (A_F32) {
                    float4 v0 = *(const float4*)(Af + gr * K + k0 + c * 8);
                    float4 v1 = *(const float4*)(Af + gr * K + k0 + c * 8 + 4);
                    w[0] = (short)f2bf(v0.x); w[1] = (short)f2bf(v0.y);
                    w[2] = (short)f2bf(v0.z); w[3] = (short)f2bf(v0.w);
                    w[4] = (short)f2bf(v1.x); w[5] = (short)f2bf(v1.y);
                    w[6] = (short)f2bf(v1.z); w[7] = (short)f2bf(v1.w);
                } else {
                    w = *(const bf16x8*)(Ab + gr * K + k0 + c * 8);
                }
            } else {
                w = (bf16x8){0, 0, 0, 0, 0, 0, 0, 0};
            }
            *(bf16x8*)(As + row * BK + sw * 8) = w;
        }
        // stage B tile (BN rows of WT x BK)
        #pragma unroll
        for (int i = 0; i < BCH / T; i++) {
            int ch = tid + i * T;
            int row = ch >> 2, c = ch & 3;
            int sw = c ^ (row & 3) ^ ((row >> 2) & 3);
            bf16x8 w = *(const bf16x8*)(WT + (long)row * K + k0 + c * 8);
            *(bf16x8*)(Bs + row * BK + sw * 8) = w;
        }
        __syncthreads();

        const int l15 = lane & 15, g = lane >> 4;
        bf16x8 a[MREP];
        #pragma unroll
        for (int mi = 0; mi < MREP; mi++) {
            int row = wr * 32 + mi * 16 + l15;
            int sw = g ^ (row & 3) ^ ((row >> 2) & 3);
            a[mi] = *(const bf16x8*)(As + row * BK + sw * 8);
        }
        #pragma unroll
        for (int ni = 0; ni < NREP; ni++) {
            int row = wc * (NREP * 16) + ni * 16 + l15;
            int sw = g ^ (row & 3) ^ ((row >> 2) & 3);
            bf16x8 b = *(const bf16x8*)(Bs + row * BK + sw * 8);
            #pragma unroll
            for (int mi = 0; mi < MREP; mi++)
                acc[mi][ni] = __builtin_amdgcn_mfma_f32_16x16x32_bf16(a[mi], b, acc[mi][ni], 0, 0, 0);
        }
        __syncthreads();
    }

    // epilogue: D row=(lane>>4)*4+q, col=lane&15 within each 16x16 tile
    const int l15 = lane & 15, l4 = lane >> 4;
    #pragma unroll
    for (int mi = 0; mi < MREP; mi++) {
        long gr0 = bm + wr * 32 + mi * 16 + l4 * 4;
        #pragma unroll
        for (int ni = 0; ni < NREP; ni++) {
            int gc = wc * (NREP * 16) + ni * 16 + l15;
            float bv = BIAS ? bias[gc] : 0.f;
            #pragma unroll
            for (int q = 0; q < 4; q++) {
                long gr = gr0 + q;
                if (gr < M) {
                    float v = acc[mi][ni][q] + bv;
                    if (RELU) v = fmaxf(v, 0.f);
                    C[gr * BN + gc] = f2bf(v);
                }
            }
        }
    }
}

// ---------------- aggregation (gather SpMM, bf16 payload) ----------------
// h1[node,f] = relu(sum_e w[e]*t1[col[e],f] + t1[node,f]*d^2 + b1[f]), bf16 out
__global__ void agg256_kernel(const unsigned short* __restrict__ t, const int* __restrict__ row_ptr,
                              const int* __restrict__ csr_col, const float* __restrict__ csr_w,
                              const float* __restrict__ dis, const float* __restrict__ bias,
                              unsigned short* __restrict__ out, int n) {
    int wid = threadIdx.x >> 6, lane = threadIdx.x & 63;
    int node = blockIdx.x * 4 + wid;
    if (node >= n) return;
    int f0 = lane * 4;
    float d = dis[node];
    float d2 = d * d;
    u16x4 sv = *(const u16x4*)(t + (long)node * NH + f0);
    float a0 = bf2f(sv[0]) * d2, a1 = bf2f(sv[1]) * d2, a2 = bf2f(sv[2]) * d2, a3 = bf2f(sv[3]) * d2;
    int lo = row_ptr[node], hi = row_ptr[node + 1];
    int e = lo;
    for (; e + 1 < hi; e += 2) {
        int c0 = csr_col[e], c1 = csr_col[e + 1];
        float w0 = csr_w[e], w1 = csr_w[e + 1];
        u16x4 v0 = *(const u16x4*)(t + (long)c0 * NH + f0);
        u16x4 v1 = *(const u16x4*)(t + (long)c1 * NH + f0);
        a0 += bf2f(v0[0]) * w0 + bf2f(v1[0]) * w1;
        a1 += bf2f(v0[1]) * w0 + bf2f(v1[1]) * w1;
        a2 += bf2f(v0[2]) * w0 + bf2f(v1[2]) * w1;
        a3 += bf2f(v0[3]) * w0 + bf2f(v1[3]) * w1;
    }
    if (e < hi) {
        int c0 = csr_col[e];
        float w0 = csr_w[e];
        u16x4 v0 = *(const u16x4*)(t + (long)c0 * NH + f0);
        a0 += bf2f(v0[0]) * w0;
        a1 += bf2f(v0[1]) * w0;
        a2 += bf2f(v0[2]) * w0;
        a3 += bf2f(v0[3]) * w0;
    }
    a0 = fmaxf(a0 + bias[f0 + 0], 0.f);
    a1 = fmaxf(a1 + bias[f0 + 1], 0.f);
    a2 = fmaxf(a2 + bias[f0 + 2], 0.f);
    a3 = fmaxf(a3 + bias[f0 + 3], 0.f);
    u16x4 o;
    o[0] = f2bf(a0); o[1] = f2bf(a1); o[2] = f2bf(a2); o[3] = f2bf(a3);
    *(u16x4*)(out + (long)node * NH + f0) = o;
}

// out[node,f<40] = sum_e w[e]*t2p[col[e],f] + t2p[node,f]*d^2 + b2[f]; t2p rows padded to 64
__global__ void agg40_kernel(const unsigned short* __restrict__ t, const int* __restrict__ row_ptr,
                             const int* __restrict__ csr_col, const float* __restrict__ csr_w,
                             const float* __restrict__ dis, const float* __restrict__ bias,
                             float* __restrict__ out, int n) {
    int wid = threadIdx.x >> 6, lane = threadIdx.x & 63;
    int node = blockIdx.x * 4 + wid;
    if (node >= n) return;
    float d = dis[node];
    float acc = bf2f(t[(long)node * 64 + lane]) * (d * d);
    int lo = row_ptr[node], hi = row_ptr[node + 1];
    int e = lo;
    for (; e + 1 < hi; e += 2) {
        int c0 = csr_col[e], c1 = csr_col[e + 1];
        float w0 = csr_w[e], w1 = csr_w[e + 1];
        acc += bf2f(t[(long)c0 * 64 + lane]) * w0 + bf2f(t[(long)c1 * 64 + lane]) * w1;
    }
    if (e < hi) {
        acc += bf2f(t[(long)csr_col[e] * 64 + lane]) * csr_w[e];
    }
    if (lane < NC) out[(long)node * NC + lane] = acc + bias[lane];
}

// ---------------- launch ----------------

extern "C" void kernel_launch(void* const* d_in, const int* in_sizes, int n_in,
                              void* d_out, int out_size, void* d_ws, size_t ws_size,
                              hipStream_t stream) {
    const float* x     = (const float*)d_in[0];
    const int*   ei    = (const int*)d_in[1];
    const float* W_mlp = (const float*)d_in[2];
    const float* b_mlp = (const float*)d_in[3];
    const float* W1    = (const float*)d_in[4];
    const float* b1    = (const float*)d_in[5];
    const float* W2    = (const float*)d_in[6];
    const float* b2    = (const float*)d_in[7];
    float* out = (float*)d_out;

    const int n = NN, E = NE;

    // workspace layout (float units)
    float* ws = (float*)d_ws;
    size_t off = 0;
    float* dis     = ws + off; off += 100096;
    int*   deg_cnt = (int*)(ws + off); off += 100096;
    int*   row_cnt = (int*)(ws + off); off += 100096;
    int*   row_ptr = (int*)(ws + off); off += 100096;
    int*   cur     = (int*)(ws + off); off += 100096;
    int*   csr_col = (int*)(ws + off); off += NE;
    float* csr_w   = ws + off; off += NE;
    unsigned short* WTm = (unsigned short*)(ws + off); off += (256 * 512) / 2;
    unsigned short* W1T = (unsigned short*)(ws + off); off += (256 * 256) / 2;
    unsigned short* W2T = (unsigned short*)(ws + off); off += (64 * 256) / 2;
    unsigned short* h0  = (unsigned short*)(ws + off); off += (size_t)NN * NH / 2;
    unsigned short* t1  = (unsigned short*)(ws + off); off += (size_t)NN * NH / 2;
    unsigned short* h1  = (unsigned short*)(ws + off); off += (size_t)NN * NH / 2;
    unsigned short* t2p = (unsigned short*)(ws + off); off += (size_t)NN * 64 / 2;
    (void)ws_size;

    hipMemsetAsync(deg_cnt, 0, n * sizeof(int), stream);
    hipMemsetAsync(row_cnt, 0, n * sizeof(int), stream);
    hipMemsetAsync(cur, 0, n * sizeof(int), stream);

    int eb = (E + 255) / 256;
    hist_kernel<<<eb, 256, 0, stream>>>(ei, deg_cnt, row_cnt, E);
    dis_kernel<<<(n + 255) / 256, 256, 0, stream>>>(deg_cnt, dis, n);
    scan_kernel<<<1, 1024, 0, stream>>>(row_cnt, row_ptr, n, E);
    fill_kernel<<<eb, 256, 0, stream>>>(ei, row_ptr, cur, dis, csr_col, csr_w, E);

    // weight transposes (bf16, [N][K] layout; W2T padded to 64 rows)
    wtrans_kernel<<<(NF * NH + 255) / 256, 256, 0, stream>>>(W_mlp, WTm, NF, NH, NH);
    wtrans_kernel<<<(NH * NH + 255) / 256, 256, 0, stream>>>(W1, W1T, NH, NH, NH);
    wtrans_kernel<<<(NH * 64 + 255) / 256, 256, 0, stream>>>(W2, W2T, NH, NC, 64);

    const int mb = (NN + 127) / 128;  // 782
    // h0 = relu(x @ W_mlp + b_mlp), bf16
    gemm_mfma<256, true, true, true><<<mb, 512, 0, stream>>>(x, WTm, b_mlp, h0, NN, NF);
    // t1 = h0 @ W1, bf16
    gemm_mfma<256, false, false, false><<<mb, 512, 0, stream>>>(h0, W1T, nullptr, t1, NN, NH);
    // h1 = relu(agg(t1) + b1), bf16
    agg256_kernel<<<(n + 3) / 4, 256, 0, stream>>>(t1, row_ptr, csr_col, csr_w, dis, b1, h1, n);
    // t2p = h1 @ W2 (padded to 64 cols), bf16
    gemm_mfma<64, false, false, false><<<mb, 256, 0, stream>>>(h1, W2T, nullptr, t2p, NN, NH);
    // out = agg(t2p) + b2, fp32
    agg40_kernel<<<(n + 3) / 4, 256, 0, stream>>>(t2p, row_ptr, csr_col, csr_w, dis, b2, out, n);
}

// Round 3
// 1025.321 us; speedup vs baseline: 2.0345x; 1.1102x over previous
//
#include <hip/hip_runtime.h>

// GCNPre: N=100000 nodes, E=3200000 edges, F=512, H=256, C=40.
#define NN 100000
#define NE 3200000
#define NF 512
#define NH 256
#define NC 40

// CSR-build partitioning: node chunks of 16384 (64KB LDS hist), edge slices.
#define CH 16384
#define NCH 7                       // 7*16384 = 114688 >= NN
#define NPAD (NCH * CH)             // 114688
#define PARTS 37
#define SLICE ((NE + PARTS - 1) / PARTS)   // 86487

typedef __attribute__((ext_vector_type(8))) short bf16x8;
typedef __attribute__((ext_vector_type(4))) float f32x4;
typedef __attribute__((ext_vector_type(4))) unsigned short u16x4;

__device__ inline unsigned short f2bf(float f) {
    union { float f; unsigned u; } v; v.f = f;
    unsigned r = v.u + 0x7fffu + ((v.u >> 16) & 1u);
    return (unsigned short)(r >> 16);
}
__device__ inline float bf2f(unsigned short s) {
    union { unsigned u; float f; } v; v.u = ((unsigned)s) << 16;
    return v.f;
}

// ---------------- CSR build (no global atomics) ----------------

// Per-(chunk, slice) LDS histogram of src[] values within [chunk*CH, chunk*CH+CH).
__global__ __launch_bounds__(512) void hist1_kernel(const int* __restrict__ src,
                                                    unsigned* __restrict__ part_out) {
    __shared__ unsigned h[CH];
    const int chunk = blockIdx.x, part = blockIdx.y;
    const int lo = chunk * CH;
    for (int i = threadIdx.x; i < CH; i += 512) h[i] = 0;
    __syncthreads();
    const int e1 = min((part + 1) * SLICE, NE);
    for (int e = part * SLICE + threadIdx.x; e < e1; e += 512) {
        unsigned v = (unsigned)(src[e] - lo);
        if (v < CH) atomicAdd(&h[v], 1u);
    }
    __syncthreads();
    unsigned* dst = part_out + (size_t)part * NPAD + lo;
    for (int i = threadIdx.x; i < CH; i += 512) dst[i] = h[i];
}

// Sum partials: row_cnt (for scan) and dis = rsqrt(deg_col + 1).
__global__ void reduce_kernel(const unsigned* __restrict__ rpart,
                              const unsigned* __restrict__ cpart,
                              int* __restrict__ row_cnt, float* __restrict__ dis) {
    int v = blockIdx.x * 256 + threadIdx.x;
    if (v >= NN) return;
    unsigned rs = 0, cs = 0;
    #pragma unroll 1
    for (int p = 0; p < PARTS; p++) {
        rs += rpart[(size_t)p * NPAD + v];
        cs += cpart[(size_t)p * NPAD + v];
    }
    row_cnt[v] = (int)rs;
    dis[v] = rsqrtf((float)cs + 1.0f);
}

// single-block exclusive scan of row_cnt -> row_ptr
__global__ void scan_kernel(const int* __restrict__ cnt, int* __restrict__ ptr, int n, int total) {
    __shared__ int s[1024];
    int t = threadIdx.x;
    int chunk = (n + 1023) / 1024;
    int lo = t * chunk, hi = min(lo + chunk, n);
    int sum = 0;
    for (int i = lo; i < hi; i++) sum += cnt[i];
    s[t] = sum;
    __syncthreads();
    for (int off = 1; off < 1024; off <<= 1) {
        int v = (t >= off) ? s[t - off] : 0;
        __syncthreads();
        s[t] += v;
        __syncthreads();
    }
    int run = (t == 0) ? 0 : s[t - 1];
    for (int i = lo; i < hi; i++) { ptr[i] = run; run += cnt[i]; }
    if (t == 0) ptr[n] = total;
}

// Turn rpart[p][v] (counts) into start offsets: row_ptr[v] + prefix over slices.
__global__ void rstart_kernel(unsigned* __restrict__ rpart, const int* __restrict__ row_ptr) {
    int v = blockIdx.x * 256 + threadIdx.x;
    if (v >= NN) return;
    unsigned run = (unsigned)row_ptr[v];
    #pragma unroll 1
    for (int p = 0; p < PARTS; p++) {
        size_t i = (size_t)p * NPAD + v;
        unsigned t = rpart[i];
        rpart[i] = run;
        run += t;
    }
}

// Fill packed CSR records {col, w} using LDS per-row counters (no global atomics).
__global__ __launch_bounds__(512) void fill2d_kernel(const int* __restrict__ ei,
                                                     const unsigned* __restrict__ rstart,
                                                     const float* __restrict__ dis,
                                                     int2* __restrict__ csr) {
    __shared__ unsigned cur[CH];
    const int chunk = blockIdx.x, part = blockIdx.y;
    const int lo = chunk * CH;
    for (int i = threadIdx.x; i < CH; i += 512) cur[i] = 0;
    __syncthreads();
    const unsigned* base = rstart + (size_t)part * NPAD + lo;
    const int e1 = min((part + 1) * SLICE, NE);
    for (int e = part * SLICE + threadIdx.x; e < e1; e += 512) {
        int r = ei[e];
        unsigned rr = (unsigned)(r - lo);
        if (rr < CH) {
            int c = ei[NE + e];
            unsigned p = atomicAdd(&cur[rr], 1u);
            unsigned idx = base[rr] + p;
            int2 rec;
            rec.x = c;
            rec.y = __float_as_int(dis[r] * dis[c]);
            csr[idx] = rec;
        }
    }
}

// ---------------- weight transpose + bf16 cast (fused) ----------------
__global__ void wtrans_all(const float* __restrict__ Wm, const float* __restrict__ W1,
                           const float* __restrict__ W2, unsigned short* __restrict__ WTm,
                           unsigned short* __restrict__ W1T, unsigned short* __restrict__ W2T) {
    int t = blockIdx.x * 256 + threadIdx.x;
    if (t < NH * NF) {                   // WTm[n][k] = Wm[k][n]
        int n = t / NF, k = t % NF;
        WTm[t] = f2bf(Wm[(long)k * NH + n]);
        return;
    }
    t -= NH * NF;
    if (t < NH * NH) {                   // W1T[n][k] = W1[k][n]
        int n = t / NH, k = t % NH;
        W1T[t] = f2bf(W1[(long)k * NH + n]);
        return;
    }
    t -= NH * NH;
    if (t < 64 * NH) {                   // W2T[n][k] = W2[k][n], padded to 64 rows
        int n = t / NH, k = t % NH;
        W2T[t] = (n < NC) ? f2bf(W2[(long)k * NC + n]) : (unsigned short)0;
    }
}

// ---------------- bf16 MFMA GEMM ----------------
template <int BN, bool A_F32, bool BIAS, bool RELU>
__global__ __launch_bounds__(BN == 256 ? 512 : 256)
void gemm_mfma(const void* __restrict__ Ap, const unsigned short* __restrict__ WT,
               const float* __restrict__ bias, unsigned short* __restrict__ C,
               int M, int K) {
    constexpr int BM = 128, BK = 32;
    constexpr int T = (BN == 256) ? 512 : 256;
    constexpr int WN = (BN == 256) ? 2 : 1;
    constexpr int NREP = BN / (WN * 16);
    constexpr int MREP = 2;
    constexpr int ACH = (BM * BK) / 8;
    constexpr int BCH = (BN * BK) / 8;

    __shared__ short As[BM * BK];
    __shared__ short Bs[BN * BK];

    const int tid = threadIdx.x;
    const int lane = tid & 63;
    const int wid = tid >> 6;
    const int wr = wid / WN;
    const int wc = wid % WN;
    const long bm = (long)blockIdx.x * BM;

    f32x4 acc[MREP][NREP];
    #pragma unroll
    for (int i = 0; i < MREP; i++)
        #pragma unroll
        for (int j = 0; j < NREP; j++)
            acc[i][j] = (f32x4){0.f, 0.f, 0.f, 0.f};

    const float* Af = (const float*)Ap;
    const unsigned short* Ab = (const unsigned short*)Ap;

    for (int k0 = 0; k0 < K; k0 += BK) {
        #pragma unroll
        for (int i = 0; i < ACH / T; i++) {
            int ch = tid + i * T;
            int row = ch >> 2, c = ch & 3;
            int sw = c ^ (row & 3) ^ ((row >> 2) & 3);
            long gr = bm + row;
            bf16x8 w;
            if (gr < M) {
                if (A_F32) {
                    float4 v0 = *(const float4*)(Af + gr * K + k0 + c * 8);
                    float4 v1 = *(const float4*)(Af + gr * K + k0 + c * 8 + 4);
                    w[0] = (short)f2bf(v0.x); w[1] = (short)f2bf(v0.y);
                    w[2] = (short)f2bf(v0.z); w[3] = (short)f2bf(v0.w);
                    w[4] = (short)f2bf(v1.x); w[5] = (short)f2bf(v1.y);
                    w[6] = (short)f2bf(v1.z); w[7] = (short)f2bf(v1.w);
                } else {
                    w = *(const bf16x8*)(Ab + gr * K + k0 + c * 8);
                }
            } else {
                w = (bf16x8){0, 0, 0, 0, 0, 0, 0, 0};
            }
            *(bf16x8*)(As + row * BK + sw * 8) = w;
        }
        #pragma unroll
        for (int i = 0; i < BCH / T; i++) {
            int ch = tid + i * T;
            int row = ch >> 2, c = ch & 3;
            int sw = c ^ (row & 3) ^ ((row >> 2) & 3);
            bf16x8 w = *(const bf16x8*)(WT + (long)row * K + k0 + c * 8);
            *(bf16x8*)(Bs + row * BK + sw * 8) = w;
        }
        __syncthreads();

        const int l15 = lane & 15, g = lane >> 4;
        bf16x8 a[MREP];
        #pragma unroll
        for (int mi = 0; mi < MREP; mi++) {
            int row = wr * 32 + mi * 16 + l15;
            int sw = g ^ (row & 3) ^ ((row >> 2) & 3);
            a[mi] = *(const bf16x8*)(As + row * BK + sw * 8);
        }
        #pragma unroll
        for (int ni = 0; ni < NREP; ni++) {
            int row = wc * (NREP * 16) + ni * 16 + l15;
            int sw = g ^ (row & 3) ^ ((row >> 2) & 3);
            bf16x8 b = *(const bf16x8*)(Bs + row * BK + sw * 8);
            #pragma unroll
            for (int mi = 0; mi < MREP; mi++)
                acc[mi][ni] = __builtin_amdgcn_mfma_f32_16x16x32_bf16(a[mi], b, acc[mi][ni], 0, 0, 0);
        }
        __syncthreads();
    }

    const int l15 = lane & 15, l4 = lane >> 4;
    #pragma unroll
    for (int mi = 0; mi < MREP; mi++) {
        long gr0 = bm + wr * 32 + mi * 16 + l4 * 4;
        #pragma unroll
        for (int ni = 0; ni < NREP; ni++) {
            int gc = wc * (NREP * 16) + ni * 16 + l15;
            float bv = BIAS ? bias[gc] : 0.f;
            #pragma unroll
            for (int q = 0; q < 4; q++) {
                long gr = gr0 + q;
                if (gr < M) {
                    float v = acc[mi][ni][q] + bv;
                    if (RELU) v = fmaxf(v, 0.f);
                    C[gr * BN + gc] = f2bf(v);
                }
            }
        }
    }
}

// ---------------- aggregation (gather SpMM, bf16 payload, packed edges) ----------------

__global__ void agg256_kernel(const unsigned short* __restrict__ t, const int* __restrict__ row_ptr,
                              const int2* __restrict__ csr, const float* __restrict__ dis,
                              const float* __restrict__ bias, unsigned short* __restrict__ out, int n) {
    int wid = threadIdx.x >> 6, lane = threadIdx.x & 63;
    int node = blockIdx.x * 4 + wid;
    if (node >= n) return;
    int f0 = lane * 4;
    float d = dis[node];
    float d2 = d * d;
    u16x4 sv = *(const u16x4*)(t + (long)node * NH + f0);
    float a0 = bf2f(sv[0]) * d2, a1 = bf2f(sv[1]) * d2, a2 = bf2f(sv[2]) * d2, a3 = bf2f(sv[3]) * d2;
    int lo = row_ptr[node], hi = row_ptr[node + 1];
    int e = lo;
    for (; e + 1 < hi; e += 2) {
        int2 r0 = csr[e], r1 = csr[e + 1];
        float w0 = __int_as_float(r0.y), w1 = __int_as_float(r1.y);
        u16x4 v0 = *(const u16x4*)(t + (long)r0.x * NH + f0);
        u16x4 v1 = *(const u16x4*)(t + (long)r1.x * NH + f0);
        a0 += bf2f(v0[0]) * w0 + bf2f(v1[0]) * w1;
        a1 += bf2f(v0[1]) * w0 + bf2f(v1[1]) * w1;
        a2 += bf2f(v0[2]) * w0 + bf2f(v1[2]) * w1;
        a3 += bf2f(v0[3]) * w0 + bf2f(v1[3]) * w1;
    }
    if (e < hi) {
        int2 r0 = csr[e];
        float w0 = __int_as_float(r0.y);
        u16x4 v0 = *(const u16x4*)(t + (long)r0.x * NH + f0);
        a0 += bf2f(v0[0]) * w0;
        a1 += bf2f(v0[1]) * w0;
        a2 += bf2f(v0[2]) * w0;
        a3 += bf2f(v0[3]) * w0;
    }
    a0 = fmaxf(a0 + bias[f0 + 0], 0.f);
    a1 = fmaxf(a1 + bias[f0 + 1], 0.f);
    a2 = fmaxf(a2 + bias[f0 + 2], 0.f);
    a3 = fmaxf(a3 + bias[f0 + 3], 0.f);
    u16x4 o;
    o[0] = f2bf(a0); o[1] = f2bf(a1); o[2] = f2bf(a2); o[3] = f2bf(a3);
    *(u16x4*)(out + (long)node * NH + f0) = o;
}

__global__ void agg40_kernel(const unsigned short* __restrict__ t, const int* __restrict__ row_ptr,
                             const int2* __restrict__ csr, const float* __restrict__ dis,
                             const float* __restrict__ bias, float* __restrict__ out, int n) {
    int wid = threadIdx.x >> 6, lane = threadIdx.x & 63;
    int node = blockIdx.x * 4 + wid;
    if (node >= n) return;
    float d = dis[node];
    float acc = bf2f(t[(long)node * 64 + lane]) * (d * d);
    int lo = row_ptr[node], hi = row_ptr[node + 1];
    int e = lo;
    for (; e + 1 < hi; e += 2) {
        int2 r0 = csr[e], r1 = csr[e + 1];
        acc += bf2f(t[(long)r0.x * 64 + lane]) * __int_as_float(r0.y)
             + bf2f(t[(long)r1.x * 64 + lane]) * __int_as_float(r1.y);
    }
    if (e < hi) {
        int2 r0 = csr[e];
        acc += bf2f(t[(long)r0.x * 64 + lane]) * __int_as_float(r0.y);
    }
    if (lane < NC) out[(long)node * NC + lane] = acc + bias[lane];
}

// ---------------- launch ----------------

extern "C" void kernel_launch(void* const* d_in, const int* in_sizes, int n_in,
                              void* d_out, int out_size, void* d_ws, size_t ws_size,
                              hipStream_t stream) {
    const float* x     = (const float*)d_in[0];
    const int*   ei    = (const int*)d_in[1];
    const float* W_mlp = (const float*)d_in[2];
    const float* b_mlp = (const float*)d_in[3];
    const float* W1    = (const float*)d_in[4];
    const float* b1    = (const float*)d_in[5];
    const float* W2    = (const float*)d_in[6];
    const float* b2    = (const float*)d_in[7];
    float* out = (float*)d_out;

    // workspace layout (float units)
    float* ws = (float*)d_ws;
    size_t off = 0;
    float*    dis     = ws + off; off += 100096;
    int*      row_cnt = (int*)(ws + off); off += 100096;
    int*      row_ptr = (int*)(ws + off); off += 100096;
    unsigned* rpart   = (unsigned*)(ws + off); off += (size_t)PARTS * NPAD;
    unsigned* cpart   = (unsigned*)(ws + off); off += (size_t)PARTS * NPAD;
    int2*     csr     = (int2*)(ws + off); off += (size_t)NE * 2;
    unsigned short* WTm = (unsigned short*)(ws + off); off += (NH * NF) / 2;
    unsigned short* W1T = (unsigned short*)(ws + off); off += (NH * NH) / 2;
    unsigned short* W2T = (unsigned short*)(ws + off); off += (64 * NH) / 2;
    unsigned short* h0  = (unsigned short*)(ws + off); off += (size_t)NN * NH / 2;
    unsigned short* t1  = (unsigned short*)(ws + off); off += (size_t)NN * NH / 2;
    unsigned short* h1  = (unsigned short*)(ws + off); off += (size_t)NN * NH / 2;
    unsigned short* t2p = (unsigned short*)(ws + off); off += (size_t)NN * 64 / 2;
    (void)ws_size;

    dim3 g2(NCH, PARTS);
    hist1_kernel<<<g2, 512, 0, stream>>>(ei, rpart);          // row counts
    hist1_kernel<<<g2, 512, 0, stream>>>(ei + NE, cpart);     // col counts (degree)
    reduce_kernel<<<(NN + 255) / 256, 256, 0, stream>>>(rpart, cpart, row_cnt, dis);
    scan_kernel<<<1, 1024, 0, stream>>>(row_cnt, row_ptr, NN, NE);
    rstart_kernel<<<(NN + 255) / 256, 256, 0, stream>>>(rpart, row_ptr);
    fill2d_kernel<<<g2, 512, 0, stream>>>(ei, rpart, dis, csr);

    wtrans_all<<<(NH * NF + NH * NH + 64 * NH + 255) / 256, 256, 0, stream>>>(
        W_mlp, W1, W2, WTm, W1T, W2T);

    const int mb = (NN + 127) / 128;  // 782
    gemm_mfma<256, true, true, true><<<mb, 512, 0, stream>>>(x, WTm, b_mlp, h0, NN, NF);
    gemm_mfma<256, false, false, false><<<mb, 512, 0, stream>>>(h0, W1T, nullptr, t1, NN, NH);
    agg256_kernel<<<(NN + 3) / 4, 256, 0, stream>>>(t1, row_ptr, csr, dis, b1, h1, NN);
    gemm_mfma<64, false, false, false><<<mb, 256, 0, stream>>>(h1, W2T, nullptr, t2p, NN, NH);
    agg40_kernel<<<(NN + 3) / 4, 256, 0, stream>>>(t2p, row_ptr, csr, dis, b2, out, NN);
}

// Round 4
// 760.542 us; speedup vs baseline: 2.7428x; 1.3481x over previous
//
#include <hip/hip_runtime.h>

// GCNPre: N=100000 nodes, E=3200000 edges, F=512, H=256, C=40.
#define NN 100000
#define NE 3200000
#define NF 512
#define NH 256
#define NC 40

// CSR-build partitioning: node chunks of 32768 (64KB LDS, packed u16x2 counters).
#define CH 32768
#define NCH 4                        // 4*32768 = 131072 >= NN
#define NPAD (NCH * CH)              // 131072
#define PARTS 64
#define SLICE ((NE + PARTS - 1) / PARTS)   // 50000

typedef __attribute__((ext_vector_type(8))) short bf16x8;
typedef __attribute__((ext_vector_type(4))) float f32x4;
typedef __attribute__((ext_vector_type(4))) unsigned short u16x4;
typedef __attribute__((ext_vector_type(8))) unsigned short u16x8;

__device__ inline unsigned short f2bf(float f) {
    union { float f; unsigned u; } v; v.f = f;
    unsigned r = v.u + 0x7fffu + ((v.u >> 16) & 1u);
    return (unsigned short)(r >> 16);
}
__device__ inline float bf2f(unsigned short s) {
    union { unsigned u; float f; } v; v.u = ((unsigned)s) << 16;
    return v.f;
}

// ---------------- CSR build (no global atomics, packed u16 LDS counters) ----------------

// blockIdx = (chunk, part, which). Histogram src[] values in [chunk*CH, chunk*CH+CH).
__global__ __launch_bounds__(512) void hist2_kernel(const int* __restrict__ ei,
                                                    unsigned short* __restrict__ rpart16,
                                                    unsigned short* __restrict__ cpart16) {
    __shared__ unsigned h[CH / 2];
    const int chunk = blockIdx.x, part = blockIdx.y, which = blockIdx.z;
    const int* src = which ? (ei + NE) : ei;
    unsigned short* outp = which ? cpart16 : rpart16;
    const int lo = chunk * CH;
    for (int i = threadIdx.x; i < CH / 2; i += 512) h[i] = 0;
    __syncthreads();
    const int e1 = min((part + 1) * SLICE, NE);
    for (int e = part * SLICE + threadIdx.x; e < e1; e += 512) {
        unsigned v = (unsigned)(src[e] - lo);
        if (v < CH) atomicAdd(&h[v >> 1], 1u << ((v & 1) << 4));
    }
    __syncthreads();
    unsigned short* dst = outp + (size_t)part * NPAD + lo;
    for (int i = threadIdx.x; i < CH; i += 512)
        dst[i] = (unsigned short)((h[i >> 1] >> ((i & 1) << 4)) & 0xffffu);
}

// Sum partials: row_cnt (for scan) and dis = rsqrt(deg_col + 1).
__global__ void reduce_kernel(const unsigned short* __restrict__ rpart16,
                              const unsigned short* __restrict__ cpart16,
                              int* __restrict__ row_cnt, float* __restrict__ dis) {
    int v = blockIdx.x * 256 + threadIdx.x;
    if (v >= NN) return;
    unsigned rs = 0, cs = 0;
    #pragma unroll 1
    for (int p = 0; p < PARTS; p++) {
        rs += rpart16[(size_t)p * NPAD + v];
        cs += cpart16[(size_t)p * NPAD + v];
    }
    row_cnt[v] = (int)rs;
    dis[v] = rsqrtf((float)cs + 1.0f);
}

// single-block exclusive scan of row_cnt -> row_ptr
__global__ void scan_kernel(const int* __restrict__ cnt, int* __restrict__ ptr, int n, int total) {
    __shared__ int s[1024];
    int t = threadIdx.x;
    int chunk = (n + 1023) / 1024;
    int lo = t * chunk, hi = min(lo + chunk, n);
    int sum = 0;
    for (int i = lo; i < hi; i++) sum += cnt[i];
    s[t] = sum;
    __syncthreads();
    for (int off = 1; off < 1024; off <<= 1) {
        int v = (t >= off) ? s[t - off] : 0;
        __syncthreads();
        s[t] += v;
        __syncthreads();
    }
    int run = (t == 0) ? 0 : s[t - 1];
    for (int i = lo; i < hi; i++) { ptr[i] = run; run += cnt[i]; }
    if (t == 0) ptr[n] = total;
}

// rbase[p][v] = row_ptr[v] + prefix of counts over slices.
__global__ void rstart_kernel(const unsigned short* __restrict__ rpart16,
                              unsigned* __restrict__ rbase, const int* __restrict__ row_ptr) {
    int v = blockIdx.x * 256 + threadIdx.x;
    if (v >= NN) return;
    unsigned run = (unsigned)row_ptr[v];
    #pragma unroll 1
    for (int p = 0; p < PARTS; p++) {
        size_t i = (size_t)p * NPAD + v;
        rbase[i] = run;
        run += rpart16[i];
    }
}

// Fill packed CSR records {col, w} with packed-u16 LDS counters.
__global__ __launch_bounds__(512) void fill2d_kernel(const int* __restrict__ ei,
                                                     const unsigned* __restrict__ rbase,
                                                     const float* __restrict__ dis,
                                                     int2* __restrict__ csr) {
    __shared__ unsigned cur[CH / 2];
    const int chunk = blockIdx.x, part = blockIdx.y;
    const int lo = chunk * CH;
    for (int i = threadIdx.x; i < CH / 2; i += 512) cur[i] = 0;
    __syncthreads();
    const unsigned* base = rbase + (size_t)part * NPAD + lo;
    const int e1 = min((part + 1) * SLICE, NE);
    for (int e = part * SLICE + threadIdx.x; e < e1; e += 512) {
        int r = ei[e];
        unsigned rr = (unsigned)(r - lo);
        if (rr < CH) {
            int c = ei[NE + e];
            unsigned sh = (rr & 1) << 4;
            unsigned old = atomicAdd(&cur[rr >> 1], 1u << sh);
            unsigned p = (old >> sh) & 0xffffu;
            unsigned idx = base[rr] + p;
            int2 rec;
            rec.x = c;
            rec.y = __float_as_int(dis[r] * dis[c]);
            csr[idx] = rec;
        }
    }
}

// ---------------- weight transpose + bf16 cast (fused) ----------------
__global__ void wtrans_all(const float* __restrict__ Wm, const float* __restrict__ W1,
                           const float* __restrict__ W2, unsigned short* __restrict__ WTm,
                           unsigned short* __restrict__ W1T, unsigned short* __restrict__ W2T) {
    int t = blockIdx.x * 256 + threadIdx.x;
    if (t < NH * NF) {                   // WTm[n][k] = Wm[k][n]
        int n = t / NF, k = t % NF;
        WTm[t] = f2bf(Wm[(long)k * NH + n]);
        return;
    }
    t -= NH * NF;
    if (t < NH * NH) {                   // W1T[n][k] = W1[k][n]
        int n = t / NH, k = t % NH;
        W1T[t] = f2bf(W1[(long)k * NH + n]);
        return;
    }
    t -= NH * NH;
    if (t < 64 * NH) {                   // W2T[n][k] = W2[k][n], padded to 64 rows
        int n = t / NH, k = t % NH;
        W2T[t] = (n < NC) ? f2bf(W2[(long)k * NC + n]) : (unsigned short)0;
    }
}

// ---------------- bf16 MFMA GEMM ----------------
template <int BN, bool A_F32, bool BIAS, bool RELU>
__global__ __launch_bounds__(BN == 256 ? 512 : 256)
void gemm_mfma(const void* __restrict__ Ap, const unsigned short* __restrict__ WT,
               const float* __restrict__ bias, unsigned short* __restrict__ C,
               int M, int K) {
    constexpr int BM = 128, BK = 32;
    constexpr int T = (BN == 256) ? 512 : 256;
    constexpr int WN = (BN == 256) ? 2 : 1;
    constexpr int NREP = BN / (WN * 16);
    constexpr int MREP = 2;
    constexpr int ACH = (BM * BK) / 8;
    constexpr int BCH = (BN * BK) / 8;

    __shared__ short As[BM * BK];
    __shared__ short Bs[BN * BK];

    const int tid = threadIdx.x;
    const int lane = tid & 63;
    const int wid = tid >> 6;
    const int wr = wid / WN;
    const int wc = wid % WN;
    const long bm = (long)blockIdx.x * BM;

    f32x4 acc[MREP][NREP];
    #pragma unroll
    for (int i = 0; i < MREP; i++)
        #pragma unroll
        for (int j = 0; j < NREP; j++)
            acc[i][j] = (f32x4){0.f, 0.f, 0.f, 0.f};

    const float* Af = (const float*)Ap;
    const unsigned short* Ab = (const unsigned short*)Ap;

    for (int k0 = 0; k0 < K; k0 += BK) {
        #pragma unroll
        for (int i = 0; i < ACH / T; i++) {
            int ch = tid + i * T;
            int row = ch >> 2, c = ch & 3;
            int sw = c ^ (row & 3) ^ ((row >> 2) & 3);
            long gr = bm + row;
            bf16x8 w;
            if (gr < M) {
                if (A_F32) {
                    float4 v0 = *(const float4*)(Af + gr * K + k0 + c * 8);
                    float4 v1 = *(const float4*)(Af + gr * K + k0 + c * 8 + 4);
                    w[0] = (short)f2bf(v0.x); w[1] = (short)f2bf(v0.y);
                    w[2] = (short)f2bf(v0.z); w[3] = (short)f2bf(v0.w);
                    w[4] = (short)f2bf(v1.x); w[5] = (short)f2bf(v1.y);
                    w[6] = (short)f2bf(v1.z); w[7] = (short)f2bf(v1.w);
                } else {
                    w = *(const bf16x8*)(Ab + gr * K + k0 + c * 8);
                }
            } else {
                w = (bf16x8){0, 0, 0, 0, 0, 0, 0, 0};
            }
            *(bf16x8*)(As + row * BK + sw * 8) = w;
        }
        #pragma unroll
        for (int i = 0; i < BCH / T; i++) {
            int ch = tid + i * T;
            int row = ch >> 2, c = ch & 3;
            int sw = c ^ (row & 3) ^ ((row >> 2) & 3);
            bf16x8 w = *(const bf16x8*)(WT + (long)row * K + k0 + c * 8);
            *(bf16x8*)(Bs + row * BK + sw * 8) = w;
        }
        __syncthreads();

        const int l15 = lane & 15, g = lane >> 4;
        bf16x8 a[MREP];
        #pragma unroll
        for (int mi = 0; mi < MREP; mi++) {
            int row = wr * 32 + mi * 16 + l15;
            int sw = g ^ (row & 3) ^ ((row >> 2) & 3);
            a[mi] = *(const bf16x8*)(As + row * BK + sw * 8);
        }
        #pragma unroll
        for (int ni = 0; ni < NREP; ni++) {
            int row = wc * (NREP * 16) + ni * 16 + l15;
            int sw = g ^ (row & 3) ^ ((row >> 2) & 3);
            bf16x8 b = *(const bf16x8*)(Bs + row * BK + sw * 8);
            #pragma unroll
            for (int mi = 0; mi < MREP; mi++)
                acc[mi][ni] = __builtin_amdgcn_mfma_f32_16x16x32_bf16(a[mi], b, acc[mi][ni], 0, 0, 0);
        }
        __syncthreads();
    }

    const int l15 = lane & 15, l4 = lane >> 4;
    #pragma unroll
    for (int mi = 0; mi < MREP; mi++) {
        long gr0 = bm + wr * 32 + mi * 16 + l4 * 4;
        #pragma unroll
        for (int ni = 0; ni < NREP; ni++) {
            int gc = wc * (NREP * 16) + ni * 16 + l15;
            float bv = BIAS ? bias[gc] : 0.f;
            #pragma unroll
            for (int q = 0; q < 4; q++) {
                long gr = gr0 + q;
                if (gr < M) {
                    float v = acc[mi][ni][q] + bv;
                    if (RELU) v = fmaxf(v, 0.f);
                    C[gr * BN + gc] = f2bf(v);
                }
            }
        }
    }
}

// ---------------- aggregation (gather SpMM, bf16 payload) ----------------
// agg256: wave = 1 node; two 32-lane halves each own alternate edges; lane gathers
// u16x8 (16B) so one instruction fetches two full 512B rows. Final shfl_xor(32).
__global__ void agg256_kernel(const unsigned short* __restrict__ t, const int* __restrict__ row_ptr,
                              const int2* __restrict__ csr, const float* __restrict__ dis,
                              const float* __restrict__ bias, unsigned short* __restrict__ out, int n) {
    const int wid = threadIdx.x >> 6, lane = threadIdx.x & 63;
    const int node = blockIdx.x * 4 + wid;
    if (node >= n) return;
    const int half = lane >> 5;
    const int f0 = (lane & 31) * 8;
    const float d = dis[node];
    float a[8];
    if (half == 0) {
        u16x8 sv = *(const u16x8*)(t + (long)node * NH + f0);
        float d2 = d * d;
        #pragma unroll
        for (int j = 0; j < 8; j++) a[j] = bf2f(sv[j]) * d2;
    } else {
        #pragma unroll
        for (int j = 0; j < 8; j++) a[j] = 0.f;
    }
    const int lo = row_ptr[node], hi = row_ptr[node + 1];
    int ee = lo + half;
    for (; ee + 2 < hi; ee += 4) {
        int2 r0 = csr[ee];
        int2 r1 = csr[ee + 2];
        u16x8 v0 = *(const u16x8*)(t + (long)r0.x * NH + f0);
        u16x8 v1 = *(const u16x8*)(t + (long)r1.x * NH + f0);
        float w0 = __int_as_float(r0.y), w1 = __int_as_float(r1.y);
        #pragma unroll
        for (int j = 0; j < 8; j++)
            a[j] += bf2f(v0[j]) * w0 + bf2f(v1[j]) * w1;
    }
    if (ee < hi) {
        int2 r0 = csr[ee];
        u16x8 v0 = *(const u16x8*)(t + (long)r0.x * NH + f0);
        float w0 = __int_as_float(r0.y);
        #pragma unroll
        for (int j = 0; j < 8; j++) a[j] += bf2f(v0[j]) * w0;
    }
    // combine halves
    #pragma unroll
    for (int j = 0; j < 8; j++) a[j] += __shfl_xor(a[j], 32);
    if (half == 0) {
        u16x8 o;
        #pragma unroll
        for (int j = 0; j < 8; j++)
            o[j] = f2bf(fmaxf(a[j] + bias[f0 + j], 0.f));
        *(u16x8*)(out + (long)node * NH + f0) = o;
    }
}

// agg40: wave = 1 node; 8 groups of 8 lanes; each group owns every-8th edge;
// lane gathers u16x8 (16B) -> one instruction fetches EIGHT 128B rows.
__global__ void agg40_kernel(const unsigned short* __restrict__ t, const int* __restrict__ row_ptr,
                             const int2* __restrict__ csr, const float* __restrict__ dis,
                             const float* __restrict__ bias, float* __restrict__ out, int n) {
    const int wid = threadIdx.x >> 6, lane = threadIdx.x & 63;
    const int node = blockIdx.x * 4 + wid;
    if (node >= n) return;
    const int g = lane >> 3;
    const int f0 = (lane & 7) * 8;
    const float d = dis[node];
    float a[8];
    if (g == 0) {
        u16x8 sv = *(const u16x8*)(t + (long)node * 64 + f0);
        float d2 = d * d;
        #pragma unroll
        for (int j = 0; j < 8; j++) a[j] = bf2f(sv[j]) * d2;
    } else {
        #pragma unroll
        for (int j = 0; j < 8; j++) a[j] = 0.f;
    }
    const int lo = row_ptr[node], hi = row_ptr[node + 1];
    int ee = lo + g;
    for (; ee + 8 < hi; ee += 16) {
        int2 r0 = csr[ee];
        int2 r1 = csr[ee + 8];
        u16x8 v0 = *(const u16x8*)(t + (long)r0.x * 64 + f0);
        u16x8 v1 = *(const u16x8*)(t + (long)r1.x * 64 + f0);
        float w0 = __int_as_float(r0.y), w1 = __int_as_float(r1.y);
        #pragma unroll
        for (int j = 0; j < 8; j++)
            a[j] += bf2f(v0[j]) * w0 + bf2f(v1[j]) * w1;
    }
    if (ee < hi) {
        int2 r0 = csr[ee];
        u16x8 v0 = *(const u16x8*)(t + (long)r0.x * 64 + f0);
        float w0 = __int_as_float(r0.y);
        #pragma unroll
        for (int j = 0; j < 8; j++) a[j] += bf2f(v0[j]) * w0;
    }
    // reduce across the 8 groups (same f0 at lanes differing in bits 3..5)
    #pragma unroll
    for (int s = 8; s < 64; s <<= 1)
        #pragma unroll
        for (int j = 0; j < 8; j++) a[j] += __shfl_xor(a[j], s);
    if (g == 0 && f0 < NC) {   // lanes 0..4: features f0..f0+7 all < 40
        float4 o0, o1;
        o0.x = a[0] + bias[f0 + 0]; o0.y = a[1] + bias[f0 + 1];
        o0.z = a[2] + bias[f0 + 2]; o0.w = a[3] + bias[f0 + 3];
        o1.x = a[4] + bias[f0 + 4]; o1.y = a[5] + bias[f0 + 5];
        o1.z = a[6] + bias[f0 + 6]; o1.w = a[7] + bias[f0 + 7];
        float* dst = out + (long)node * NC + f0;
        *(float4*)dst = o0;
        *(float4*)(dst + 4) = o1;
    }
}

// ---------------- launch ----------------

extern "C" void kernel_launch(void* const* d_in, const int* in_sizes, int n_in,
                              void* d_out, int out_size, void* d_ws, size_t ws_size,
                              hipStream_t stream) {
    const float* x     = (const float*)d_in[0];
    const int*   ei    = (const int*)d_in[1];
    const float* W_mlp = (const float*)d_in[2];
    const float* b_mlp = (const float*)d_in[3];
    const float* W1    = (const float*)d_in[4];
    const float* b1    = (const float*)d_in[5];
    const float* W2    = (const float*)d_in[6];
    const float* b2    = (const float*)d_in[7];
    float* out = (float*)d_out;

    // workspace layout (float units)
    float* ws = (float*)d_ws;
    size_t off = 0;
    float*    dis     = ws + off; off += 100096;
    int*      row_cnt = (int*)(ws + off); off += 100096;
    int*      row_ptr = (int*)(ws + off); off += 100096;
    unsigned short* rpart16 = (unsigned short*)(ws + off); off += (size_t)PARTS * NPAD / 2;
    unsigned short* cpart16 = (unsigned short*)(ws + off); off += (size_t)PARTS * NPAD / 2;
    unsigned* rbase   = (unsigned*)(ws + off); off += (size_t)PARTS * NPAD;
    int2*     csr     = (int2*)(ws + off); off += (size_t)NE * 2;
    unsigned short* WTm = (unsigned short*)(ws + off); off += (NH * NF) / 2;
    unsigned short* W1T = (unsigned short*)(ws + off); off += (NH * NH) / 2;
    unsigned short* W2T = (unsigned short*)(ws + off); off += (64 * NH) / 2;
    unsigned short* h0  = (unsigned short*)(ws + off); off += (size_t)NN * NH / 2;
    unsigned short* t1  = (unsigned short*)(ws + off); off += (size_t)NN * NH / 2;
    unsigned short* t2p = (unsigned short*)(ws + off); off += (size_t)NN * 64 / 2;
    unsigned short* h1  = h0;   // h0 dead after gemm2; alias to save 51MB
    (void)ws_size;

    dim3 gh(NCH, PARTS, 2);
    hist2_kernel<<<gh, 512, 0, stream>>>(ei, rpart16, cpart16);
    reduce_kernel<<<(NN + 255) / 256, 256, 0, stream>>>(rpart16, cpart16, row_cnt, dis);
    scan_kernel<<<1, 1024, 0, stream>>>(row_cnt, row_ptr, NN, NE);
    rstart_kernel<<<(NN + 255) / 256, 256, 0, stream>>>(rpart16, rbase, row_ptr);
    dim3 gf(NCH, PARTS);
    fill2d_kernel<<<gf, 512, 0, stream>>>(ei, rbase, dis, csr);

    wtrans_all<<<(NH * NF + NH * NH + 64 * NH + 255) / 256, 256, 0, stream>>>(
        W_mlp, W1, W2, WTm, W1T, W2T);

    const int mb = (NN + 127) / 128;  // 782
    gemm_mfma<256, true, true, true><<<mb, 512, 0, stream>>>(x, WTm, b_mlp, h0, NN, NF);
    gemm_mfma<256, false, false, false><<<mb, 512, 0, stream>>>(h0, W1T, nullptr, t1, NN, NH);
    agg256_kernel<<<(NN + 3) / 4, 256, 0, stream>>>(t1, row_ptr, csr, dis, b1, h1, NN);
    gemm_mfma<64, false, false, false><<<mb, 256, 0, stream>>>(h1, W2T, nullptr, t2p, NN, NH);
    agg40_kernel<<<(NN + 3) / 4, 256, 0, stream>>>(t2p, row_ptr, csr, dis, b2, out, NN);
}

// Round 5
// 602.910 us; speedup vs baseline: 3.4599x; 1.2615x over previous
//
#include <hip/hip_runtime.h>

// GCNPre: N=100000 nodes, E=3200000 edges, F=512, H=256, C=40.
#define NN 100000
#define NE 3200000
#define NF 512
#define NH 256
#define NC 40

// CSR-build partitioning: node chunks of 32768 (64KB LDS, packed u16x2 counters).
#define CH 32768
#define NCH 4                        // 4*32768 = 131072 >= NN
#define NPAD (NCH * CH)              // 131072
#define PARTS 64
#define SLICE ((NE + PARTS - 1) / PARTS)   // 50000
#define NBLK ((NN + 255) / 256)      // 391 -> ceil = 391? (100000+255)/256 = 391.6 -> 392

typedef __attribute__((ext_vector_type(8))) short bf16x8;
typedef __attribute__((ext_vector_type(4))) float f32x4;
typedef __attribute__((ext_vector_type(4))) unsigned short u16x4;
typedef __attribute__((ext_vector_type(8))) unsigned short u16x8;

__device__ inline unsigned short f2bf(float f) {
    union { float f; unsigned u; } v; v.f = f;
    unsigned r = v.u + 0x7fffu + ((v.u >> 16) & 1u);
    return (unsigned short)(r >> 16);
}
__device__ inline float bf2f(unsigned short s) {
    union { unsigned u; float f; } v; v.u = ((unsigned)s) << 16;
    return v.f;
}

// ---------------- CSR build (no global atomics, packed u16 LDS counters) ----------------

// blockIdx = (chunk, part, which). Histogram src[] values in [chunk*CH, chunk*CH+CH).
__global__ __launch_bounds__(512) void hist2_kernel(const int* __restrict__ ei,
                                                    unsigned short* __restrict__ rpart16,
                                                    unsigned short* __restrict__ cpart16) {
    __shared__ unsigned h[CH / 2];
    const int chunk = blockIdx.x, part = blockIdx.y, which = blockIdx.z;
    const int* src = which ? (ei + NE) : ei;
    unsigned short* outp = which ? cpart16 : rpart16;
    const int lo = chunk * CH;
    for (int i = threadIdx.x; i < CH / 2; i += 512) h[i] = 0;
    __syncthreads();
    const int e1 = min((part + 1) * SLICE, NE);
    for (int e = part * SLICE + threadIdx.x; e < e1; e += 512) {
        unsigned v = (unsigned)(src[e] - lo);
        if (v < CH) atomicAdd(&h[v >> 1], 1u << ((v & 1) << 4));
    }
    __syncthreads();
    // flush as u32 pairs
    unsigned* dst = (unsigned*)(outp + (size_t)part * NPAD + lo);
    for (int i = threadIdx.x; i < CH / 2; i += 512) dst[i] = h[i];
}

// Sum partials -> row_cnt, dis; also block sum of row_cnt -> bsum[block].
__global__ __launch_bounds__(256) void reduce_kernel(const unsigned short* __restrict__ rpart16,
                                                     const unsigned short* __restrict__ cpart16,
                                                     int* __restrict__ row_cnt, float* __restrict__ dis,
                                                     int* __restrict__ bsum) {
    __shared__ int s[256];
    const int tid = threadIdx.x;
    const int v = blockIdx.x * 256 + tid;
    unsigned rs = 0, cs = 0;
    if (v < NN) {
        #pragma unroll 1
        for (int p = 0; p < PARTS; p++) {
            rs += rpart16[(size_t)p * NPAD + v];
            cs += cpart16[(size_t)p * NPAD + v];
        }
        row_cnt[v] = (int)rs;
        dis[v] = rsqrtf((float)cs + 1.0f);
    }
    s[tid] = (int)rs;
    __syncthreads();
    #pragma unroll
    for (int o = 128; o > 0; o >>= 1) {
        if (tid < o) s[tid] += s[tid + o];
        __syncthreads();
    }
    if (tid == 0) bsum[blockIdx.x] = s[0];
}

// Exclusive scan of NBLK block sums (single small block).
__global__ __launch_bounds__(512) void scanb_kernel(const int* __restrict__ bsum,
                                                    int* __restrict__ boff) {
    __shared__ int s[512];
    const int t = threadIdx.x;
    int v = (t < NBLK) ? bsum[t] : 0;
    s[t] = v;
    __syncthreads();
    #pragma unroll
    for (int o = 1; o < 512; o <<= 1) {
        int u = (t >= o) ? s[t - o] : 0;
        __syncthreads();
        s[t] += u;
        __syncthreads();
    }
    if (t < NBLK) boff[t] = s[t] - v;   // exclusive
}

// row_ptr[v] = boff[blk] + intra-block exclusive scan; rbase[p][v] = prefix over slices.
__global__ __launch_bounds__(256) void rstart2_kernel(const unsigned short* __restrict__ rpart16,
                                                      const int* __restrict__ row_cnt,
                                                      const int* __restrict__ boff,
                                                      int* __restrict__ row_ptr,
                                                      unsigned* __restrict__ rbase) {
    __shared__ int s[256];
    const int tid = threadIdx.x;
    const int v = blockIdx.x * 256 + tid;
    int cnt = (v < NN) ? row_cnt[v] : 0;
    s[tid] = cnt;
    __syncthreads();
    #pragma unroll
    for (int o = 1; o < 256; o <<= 1) {
        int u = (tid >= o) ? s[tid - o] : 0;
        __syncthreads();
        s[tid] += u;
        __syncthreads();
    }
    if (v < NN) {
        unsigned run = (unsigned)(boff[blockIdx.x] + s[tid] - cnt);
        row_ptr[v] = (int)run;
        #pragma unroll 1
        for (int p = 0; p < PARTS; p++) {
            size_t i = (size_t)p * NPAD + v;
            rbase[i] = run;
            run += rpart16[i];
        }
    }
    if (v == NN) row_ptr[NN] = NE;
}

// Fill packed CSR records {col, w} with packed-u16 LDS counters.
__global__ __launch_bounds__(512) void fill2d_kernel(const int* __restrict__ ei,
                                                     const unsigned* __restrict__ rbase,
                                                     const float* __restrict__ dis,
                                                     int2* __restrict__ csr) {
    __shared__ unsigned cur[CH / 2];
    const int chunk = blockIdx.x, part = blockIdx.y;
    const int lo = chunk * CH;
    for (int i = threadIdx.x; i < CH / 2; i += 512) cur[i] = 0;
    __syncthreads();
    const unsigned* base = rbase + (size_t)part * NPAD + lo;
    const int e1 = min((part + 1) * SLICE, NE);
    for (int e = part * SLICE + threadIdx.x; e < e1; e += 512) {
        int r = ei[e];
        unsigned rr = (unsigned)(r - lo);
        if (rr < CH) {
            int c = ei[NE + e];
            unsigned sh = (rr & 1) << 4;
            unsigned old = atomicAdd(&cur[rr >> 1], 1u << sh);
            unsigned p = (old >> sh) & 0xffffu;
            unsigned idx = base[rr] + p;
            int2 rec;
            rec.x = c;
            rec.y = __float_as_int(dis[r] * dis[c]);
            csr[idx] = rec;
        }
    }
}

// ---------------- weight transpose + bf16 cast (fused) ----------------
__global__ void wtrans_all(const float* __restrict__ Wm, const float* __restrict__ W1,
                           const float* __restrict__ W2, unsigned short* __restrict__ WTm,
                           unsigned short* __restrict__ W1T, unsigned short* __restrict__ W2T) {
    int t = blockIdx.x * 256 + threadIdx.x;
    if (t < NH * NF) {                   // WTm[n][k] = Wm[k][n]
        int n = t / NF, k = t % NF;
        WTm[t] = f2bf(Wm[(long)k * NH + n]);
        return;
    }
    t -= NH * NF;
    if (t < NH * NH) {                   // W1T[n][k] = W1[k][n]
        int n = t / NH, k = t % NH;
        W1T[t] = f2bf(W1[(long)k * NH + n]);
        return;
    }
    t -= NH * NH;
    if (t < 64 * NH) {                   // W2T[n][k] = W2[k][n], padded to 64 rows
        int n = t / NH, k = t % NH;
        W2T[t] = (n < NC) ? f2bf(W2[(long)k * NC + n]) : (unsigned short)0;
    }
}

// ---------------- bf16 MFMA GEMM ----------------
template <int BN, bool A_F32, bool BIAS, bool RELU>
__global__ __launch_bounds__(BN == 256 ? 512 : 256)
void gemm_mfma(const void* __restrict__ Ap, const unsigned short* __restrict__ WT,
               const float* __restrict__ bias, unsigned short* __restrict__ C,
               int M, int K) {
    constexpr int BM = 128, BK = 32;
    constexpr int T = (BN == 256) ? 512 : 256;
    constexpr int WN = (BN == 256) ? 2 : 1;
    constexpr int NREP = BN / (WN * 16);
    constexpr int MREP = 2;
    constexpr int ACH = (BM * BK) / 8;
    constexpr int BCH = (BN * BK) / 8;

    __shared__ short As[BM * BK];
    __shared__ short Bs[BN * BK];

    const int tid = threadIdx.x;
    const int lane = tid & 63;
    const int wid = tid >> 6;
    const int wr = wid / WN;
    const int wc = wid % WN;
    const long bm = (long)blockIdx.x * BM;

    f32x4 acc[MREP][NREP];
    #pragma unroll
    for (int i = 0; i < MREP; i++)
        #pragma unroll
        for (int j = 0; j < NREP; j++)
            acc[i][j] = (f32x4){0.f, 0.f, 0.f, 0.f};

    const float* Af = (const float*)Ap;
    const unsigned short* Ab = (const unsigned short*)Ap;

    for (int k0 = 0; k0 < K; k0 += BK) {
        #pragma unroll
        for (int i = 0; i < ACH / T; i++) {
            int ch = tid + i * T;
            int row = ch >> 2, c = ch & 3;
            int sw = c ^ (row & 3) ^ ((row >> 2) & 3);
            long gr = bm + row;
            bf16x8 w;
            if (gr < M) {
                if (A_F32) {
                    float4 v0 = *(const float4*)(Af + gr * K + k0 + c * 8);
                    float4 v1 = *(const float4*)(Af + gr * K + k0 + c * 8 + 4);
                    w[0] = (short)f2bf(v0.x); w[1] = (short)f2bf(v0.y);
                    w[2] = (short)f2bf(v0.z); w[3] = (short)f2bf(v0.w);
                    w[4] = (short)f2bf(v1.x); w[5] = (short)f2bf(v1.y);
                    w[6] = (short)f2bf(v1.z); w[7] = (short)f2bf(v1.w);
                } else {
                    w = *(const bf16x8*)(Ab + gr * K + k0 + c * 8);
                }
            } else {
                w = (bf16x8){0, 0, 0, 0, 0, 0, 0, 0};
            }
            *(bf16x8*)(As + row * BK + sw * 8) = w;
        }
        #pragma unroll
        for (int i = 0; i < BCH / T; i++) {
            int ch = tid + i * T;
            int row = ch >> 2, c = ch & 3;
            int sw = c ^ (row & 3) ^ ((row >> 2) & 3);
            bf16x8 w = *(const bf16x8*)(WT + (long)row * K + k0 + c * 8);
            *(bf16x8*)(Bs + row * BK + sw * 8) = w;
        }
        __syncthreads();

        const int l15 = lane & 15, g = lane >> 4;
        bf16x8 a[MREP];
        #pragma unroll
        for (int mi = 0; mi < MREP; mi++) {
            int row = wr * 32 + mi * 16 + l15;
            int sw = g ^ (row & 3) ^ ((row >> 2) & 3);
            a[mi] = *(const bf16x8*)(As + row * BK + sw * 8);
        }
        #pragma unroll
        for (int ni = 0; ni < NREP; ni++) {
            int row = wc * (NREP * 16) + ni * 16 + l15;
            int sw = g ^ (row & 3) ^ ((row >> 2) & 3);
            bf16x8 b = *(const bf16x8*)(Bs + row * BK + sw * 8);
            #pragma unroll
            for (int mi = 0; mi < MREP; mi++)
                acc[mi][ni] = __builtin_amdgcn_mfma_f32_16x16x32_bf16(a[mi], b, acc[mi][ni], 0, 0, 0);
        }
        __syncthreads();
    }

    const int l15 = lane & 15, l4 = lane >> 4;
    #pragma unroll
    for (int mi = 0; mi < MREP; mi++) {
        long gr0 = bm + wr * 32 + mi * 16 + l4 * 4;
        #pragma unroll
        for (int ni = 0; ni < NREP; ni++) {
            int gc = wc * (NREP * 16) + ni * 16 + l15;
            float bv = BIAS ? bias[gc] : 0.f;
            #pragma unroll
            for (int q = 0; q < 4; q++) {
                long gr = gr0 + q;
                if (gr < M) {
                    float v = acc[mi][ni][q] + bv;
                    if (RELU) v = fmaxf(v, 0.f);
                    C[gr * BN + gc] = f2bf(v);
                }
            }
        }
    }
}

// ---------------- aggregation (gather SpMM, bf16 payload) ----------------
// agg256: wave = 1 node; two 32-lane halves own alternate edges; lane gathers
// u16x8 (16B) so one instruction fetches two full 512B rows. 4-deep unroll.
__global__ void agg256_kernel(const unsigned short* __restrict__ t, const int* __restrict__ row_ptr,
                              const int2* __restrict__ csr, const float* __restrict__ dis,
                              const float* __restrict__ bias, unsigned short* __restrict__ out, int n) {
    const int wid = threadIdx.x >> 6, lane = threadIdx.x & 63;
    const int node = blockIdx.x * 4 + wid;
    if (node >= n) return;
    const int half = lane >> 5;
    const int f0 = (lane & 31) * 8;
    const float d = dis[node];
    float a[8];
    if (half == 0) {
        u16x8 sv = *(const u16x8*)(t + (long)node * NH + f0);
        float d2 = d * d;
        #pragma unroll
        for (int j = 0; j < 8; j++) a[j] = bf2f(sv[j]) * d2;
    } else {
        #pragma unroll
        for (int j = 0; j < 8; j++) a[j] = 0.f;
    }
    const int lo = row_ptr[node], hi = row_ptr[node + 1];
    int ee = lo + half;
    for (; ee + 6 < hi; ee += 8) {
        int2 r0 = csr[ee];
        int2 r1 = csr[ee + 2];
        int2 r2 = csr[ee + 4];
        int2 r3 = csr[ee + 6];
        u16x8 v0 = *(const u16x8*)(t + (long)r0.x * NH + f0);
        u16x8 v1 = *(const u16x8*)(t + (long)r1.x * NH + f0);
        u16x8 v2 = *(const u16x8*)(t + (long)r2.x * NH + f0);
        u16x8 v3 = *(const u16x8*)(t + (long)r3.x * NH + f0);
        float w0 = __int_as_float(r0.y), w1 = __int_as_float(r1.y);
        float w2 = __int_as_float(r2.y), w3 = __int_as_float(r3.y);
        #pragma unroll
        for (int j = 0; j < 8; j++)
            a[j] += (bf2f(v0[j]) * w0 + bf2f(v1[j]) * w1) + (bf2f(v2[j]) * w2 + bf2f(v3[j]) * w3);
    }
    for (; ee + 2 < hi; ee += 4) {
        int2 r0 = csr[ee];
        int2 r1 = csr[ee + 2];
        u16x8 v0 = *(const u16x8*)(t + (long)r0.x * NH + f0);
        u16x8 v1 = *(const u16x8*)(t + (long)r1.x * NH + f0);
        float w0 = __int_as_float(r0.y), w1 = __int_as_float(r1.y);
        #pragma unroll
        for (int j = 0; j < 8; j++)
            a[j] += bf2f(v0[j]) * w0 + bf2f(v1[j]) * w1;
    }
    if (ee < hi) {
        int2 r0 = csr[ee];
        u16x8 v0 = *(const u16x8*)(t + (long)r0.x * NH + f0);
        float w0 = __int_as_float(r0.y);
        #pragma unroll
        for (int j = 0; j < 8; j++) a[j] += bf2f(v0[j]) * w0;
    }
    #pragma unroll
    for (int j = 0; j < 8; j++) a[j] += __shfl_xor(a[j], 32);
    if (half == 0) {
        u16x8 o;
        #pragma unroll
        for (int j = 0; j < 8; j++)
            o[j] = f2bf(fmaxf(a[j] + bias[f0 + j], 0.f));
        *(u16x8*)(out + (long)node * NH + f0) = o;
    }
}

// agg40: wave = 1 node; 8 groups of 8 lanes; each group owns every-8th edge;
// lane gathers u16x8 (16B) -> one instruction fetches EIGHT 128B rows.
__global__ void agg40_kernel(const unsigned short* __restrict__ t, const int* __restrict__ row_ptr,
                             const int2* __restrict__ csr, const float* __restrict__ dis,
                             const float* __restrict__ bias, float* __restrict__ out, int n) {
    const int wid = threadIdx.x >> 6, lane = threadIdx.x & 63;
    const int node = blockIdx.x * 4 + wid;
    if (node >= n) return;
    const int g = lane >> 3;
    const int f0 = (lane & 7) * 8;
    const float d = dis[node];
    float a[8];
    if (g == 0) {
        u16x8 sv = *(const u16x8*)(t + (long)node * 64 + f0);
        float d2 = d * d;
        #pragma unroll
        for (int j = 0; j < 8; j++) a[j] = bf2f(sv[j]) * d2;
    } else {
        #pragma unroll
        for (int j = 0; j < 8; j++) a[j] = 0.f;
    }
    const int lo = row_ptr[node], hi = row_ptr[node + 1];
    int ee = lo + g;
    for (; ee + 8 < hi; ee += 16) {
        int2 r0 = csr[ee];
        int2 r1 = csr[ee + 8];
        u16x8 v0 = *(const u16x8*)(t + (long)r0.x * 64 + f0);
        u16x8 v1 = *(const u16x8*)(t + (long)r1.x * 64 + f0);
        float w0 = __int_as_float(r0.y), w1 = __int_as_float(r1.y);
        #pragma unroll
        for (int j = 0; j < 8; j++)
            a[j] += bf2f(v0[j]) * w0 + bf2f(v1[j]) * w1;
    }
    if (ee < hi) {
        int2 r0 = csr[ee];
        u16x8 v0 = *(const u16x8*)(t + (long)r0.x * 64 + f0);
        float w0 = __int_as_float(r0.y);
        #pragma unroll
        for (int j = 0; j < 8; j++) a[j] += bf2f(v0[j]) * w0;
    }
    #pragma unroll
    for (int s = 8; s < 64; s <<= 1)
        #pragma unroll
        for (int j = 0; j < 8; j++) a[j] += __shfl_xor(a[j], s);
    if (g == 0 && f0 < NC) {
        float4 o0, o1;
        o0.x = a[0] + bias[f0 + 0]; o0.y = a[1] + bias[f0 + 1];
        o0.z = a[2] + bias[f0 + 2]; o0.w = a[3] + bias[f0 + 3];
        o1.x = a[4] + bias[f0 + 4]; o1.y = a[5] + bias[f0 + 5];
        o1.z = a[6] + bias[f0 + 6]; o1.w = a[7] + bias[f0 + 7];
        float* dst = out + (long)node * NC + f0;
        *(float4*)dst = o0;
        *(float4*)(dst + 4) = o1;
    }
}

// ---------------- launch ----------------

extern "C" void kernel_launch(void* const* d_in, const int* in_sizes, int n_in,
                              void* d_out, int out_size, void* d_ws, size_t ws_size,
                              hipStream_t stream) {
    const float* x     = (const float*)d_in[0];
    const int*   ei    = (const int*)d_in[1];
    const float* W_mlp = (const float*)d_in[2];
    const float* b_mlp = (const float*)d_in[3];
    const float* W1    = (const float*)d_in[4];
    const float* b1    = (const float*)d_in[5];
    const float* W2    = (const float*)d_in[6];
    const float* b2    = (const float*)d_in[7];
    float* out = (float*)d_out;

    // workspace layout (float units)
    float* ws = (float*)d_ws;
    size_t off = 0;
    float*    dis     = ws + off; off += 100096;
    int*      row_cnt = (int*)(ws + off); off += 100096;
    int*      row_ptr = (int*)(ws + off); off += 100096;
    int*      bsum    = (int*)(ws + off); off += 512;
    int*      boff    = (int*)(ws + off); off += 512;
    unsigned short* rpart16 = (unsigned short*)(ws + off); off += (size_t)PARTS * NPAD / 2;
    unsigned short* cpart16 = (unsigned short*)(ws + off); off += (size_t)PARTS * NPAD / 2;
    unsigned* rbase   = (unsigned*)(ws + off); off += (size_t)PARTS * NPAD;
    int2*     csr     = (int2*)(ws + off); off += (size_t)NE * 2;
    unsigned short* WTm = (unsigned short*)(ws + off); off += (NH * NF) / 2;
    unsigned short* W1T = (unsigned short*)(ws + off); off += (NH * NH) / 2;
    unsigned short* W2T = (unsigned short*)(ws + off); off += (64 * NH) / 2;
    unsigned short* h0  = (unsigned short*)(ws + off); off += (size_t)NN * NH / 2;
    unsigned short* t1  = (unsigned short*)(ws + off); off += (size_t)NN * NH / 2;
    unsigned short* t2p = (unsigned short*)(ws + off); off += (size_t)NN * 64 / 2;
    unsigned short* h1  = h0;   // h0 dead after gemm2; alias to save 51MB
    (void)ws_size;

    dim3 gh(NCH, PARTS, 2);
    hist2_kernel<<<gh, 512, 0, stream>>>(ei, rpart16, cpart16);
    reduce_kernel<<<NBLK, 256, 0, stream>>>(rpart16, cpart16, row_cnt, dis, bsum);
    scanb_kernel<<<1, 512, 0, stream>>>(bsum, boff);
    rstart2_kernel<<<NBLK, 256, 0, stream>>>(rpart16, row_cnt, boff, row_ptr, rbase);
    dim3 gf(NCH, PARTS);
    fill2d_kernel<<<gf, 512, 0, stream>>>(ei, rbase, dis, csr);

    wtrans_all<<<(NH * NF + NH * NH + 64 * NH + 255) / 256, 256, 0, stream>>>(
        W_mlp, W1, W2, WTm, W1T, W2T);

    const int mb = (NN + 127) / 128;  // 782
    gemm_mfma<256, true, true, true><<<mb, 512, 0, stream>>>(x, WTm, b_mlp, h0, NN, NF);
    gemm_mfma<256, false, false, false><<<mb, 512, 0, stream>>>(h0, W1T, nullptr, t1, NN, NH);
    agg256_kernel<<<(NN + 3) / 4, 256, 0, stream>>>(t1, row_ptr, csr, dis, b1, h1, NN);
    gemm_mfma<64, false, false, false><<<mb, 256, 0, stream>>>(h1, W2T, nullptr, t2p, NN, NH);
    agg40_kernel<<<(NN + 3) / 4, 256, 0, stream>>>(t2p, row_ptr, csr, dis, b2, out, NN);
}